// Round 14
// baseline (478.747 us; speedup 1.0000x reference)
//
#include <hip/hip_runtime.h>
#include <hip/hip_bf16.h>
#include <cstddef>
#include <cstdint>

// Problem constants (match reference setup_inputs)
constexpr int NN    = 50000;   // nodes
constexpr int EE    = 500000;  // edges
constexpr int FF    = 128;     // input feature dim
constexpr int HIDC  = 64;      // hidden per head
constexpr int NHEAD = 4;
constexpr int HC    = 256;     // NHEAD * HIDC
constexpr int GG    = 256;     // graphs

typedef __attribute__((ext_vector_type(2))) float f32x2;
typedef __attribute__((ext_vector_type(4))) float f32x4;
typedef __attribute__((ext_vector_type(8))) short bf16x8;

// CSR edge record: src byte-offset (src*1024) + the 6 edge features. 32 B.
struct __align__(16) EPack { int soff; int pad; float e0, e1, e2, e3, e4, e5; };

// round-to-nearest-even fp32 -> bf16 (as short)
__device__ inline short f2bf(float f) {
  union { float f; unsigned u; } v; v.f = f;
  unsigned r = v.u + 0x7fffu + ((v.u >> 16) & 1u);
  return (short)(r >> 16);
}

// unpack 4 bf16 (as uint2) -> two f32x2
__device__ inline void bf4_unpack(uint2 v, f32x2& a, f32x2& b) {
  union { unsigned u; float f; } t;
  t.u = v.x << 16;          a.x = t.f;
  t.u = v.x & 0xffff0000u;  a.y = t.f;
  t.u = v.y << 16;          b.x = t.f;
  t.u = v.y & 0xffff0000u;  b.y = t.f;
}

// ---------------------------------------------------------------------------
// Weight-conversion job table (all 6 matrices)
// ---------------------------------------------------------------------------
struct WtJobs {
  const float* w[6];
  short* o[6];
  int K[6], N[6];
  int cum[7];
};

// ---------------------------------------------------------------------------
// Prep kernel: convert x -> bf16, convert all weights (transpose+bf16),
// zero pairs tail, AND count degrees (deg/gp zeroed by hipMemsetAsync).
// ---------------------------------------------------------------------------
__global__ void prep_all(const float* __restrict__ x, short* __restrict__ xbf,
                         const int* __restrict__ dst, int* __restrict__ deg,
                         int* __restrict__ pairs_tail, WtJobs j) {
  int i = blockIdx.x * blockDim.x + threadIdx.x;
  if (i < NN * FF) xbf[i] = f2bf(x[i]);
  if (i < EE) atomicAdd(&deg[dst[i]], 1);      // folded count_deg
  if (i < 16 * 8) pairs_tail[i] = 0;           // 16 EPack tail entries
  if (i < j.cum[6]) {
    int s = 0;
    while (i >= j.cum[s + 1]) s++;
    int li = i - j.cum[s];
    int K = j.K[s], N = j.N[s];
    int n = li / K, k = li - n * K;
    j.o[s][li] = f2bf(j.w[s][k * N + n]);
  }
}

constexpr int SCAN_T = 256;   // threads per scan block
constexpr int SCAN_B = 64;    // scan blocks
constexpr int SCHUNK = 4;     // elems per thread (64*256*4 = 65536 >= NN)

// Stage 1: per-block sums of deg
__global__ __launch_bounds__(SCAN_T) void scan_stage1(const int* __restrict__ deg,
                                                      int* __restrict__ bsum) {
  __shared__ int red[SCAN_T];
  const int t = threadIdx.x, b = blockIdx.x;
  int base = (b * SCAN_T + t) * SCHUNK;
  int s = 0;
  #pragma unroll
  for (int i = 0; i < SCHUNK; i++) {
    int idx = base + i;
    if (idx < NN) s += deg[idx];
  }
  red[t] = s;
  __syncthreads();
  for (int off = SCAN_T / 2; off > 0; off >>= 1) {
    if (t < off) red[t] += red[t + off];
    __syncthreads();
  }
  if (t == 0) bsum[b] = red[0];
}

// Stage 2: inclusive scan of the 64 block sums (one wave)
__global__ __launch_bounds__(64) void scan_stage2(int* __restrict__ bsum) {
  int t = threadIdx.x;
  int v = bsum[t];
  #pragma unroll
  for (int off = 1; off < 64; off <<= 1) {
    int o = __shfl_up(v, off, 64);
    if (t >= off) v += o;
  }
  bsum[t] = v;   // inclusive
}

// Stage 3: full exclusive prefix -> offs/cur (+ offs[NN] = total)
__global__ __launch_bounds__(SCAN_T) void scan_stage3(const int* __restrict__ deg,
                                                      const int* __restrict__ bsum,
                                                      int* __restrict__ offs,
                                                      int* __restrict__ cur) {
  __shared__ int red[SCAN_T];
  const int t = threadIdx.x, b = blockIdx.x;
  const int base = (b * SCAN_T + t) * SCHUNK;
  int local[SCHUNK];
  int s = 0;
  #pragma unroll
  for (int i = 0; i < SCHUNK; i++) {
    int idx = base + i;
    local[i] = (idx < NN) ? deg[idx] : 0;
    s += local[i];
  }
  red[t] = s;
  __syncthreads();
  for (int off = 1; off < SCAN_T; off <<= 1) {   // Hillis-Steele inclusive
    int v = (t >= off) ? red[t - off] : 0;
    __syncthreads();
    red[t] += v;
    __syncthreads();
  }
  const int blockBase = (b == 0) ? 0 : bsum[b - 1];
  int run = blockBase + red[t] - s;              // exclusive prefix for this thread
  #pragma unroll
  for (int i = 0; i < SCHUNK; i++) {
    int idx = base + i;
    if (idx < NN) {
      offs[idx] = run; cur[idx] = run; run += local[i];
    }
  }
  if (b == SCAN_B - 1 && t == SCAN_T - 1) offs[NN] = run;  // == EE
}

__global__ void fill_edges(const int* __restrict__ src, const int* __restrict__ dst,
                           const float* __restrict__ eattr,
                           int* __restrict__ cur, EPack* __restrict__ pairs) {
  int i = blockIdx.x * blockDim.x + threadIdx.x;
  if (i < EE) {
    int pos = atomicAdd(&cur[dst[i]], 1);
    const float* ea = eattr + i * 6;
    int4* q = (int4*)(pairs + pos);
    int4 w0, w1;
    w0.x = src[i] * 1024; w0.y = 0;
    w0.z = __float_as_int(ea[0]); w0.w = __float_as_int(ea[1]);
    w1.x = __float_as_int(ea[2]); w1.y = __float_as_int(ea[3]);
    w1.z = __float_as_int(ea[4]); w1.w = __float_as_int(ea[5]);
    q[0] = w0; q[1] = w1;
  }
}

// ---------------------------------------------------------------------------
// bf16 MFMA GEMM, 128x128 tile, BK=64, 256 threads (2x2 waves of 64x64).
// B fragments direct from global (L2-resident weights); LDS only for A.
// R5: XCD-co-location swizzle. R11: A-tile issue-early/write-late (−9us).
// R12: all-B hoist (neutral, kept). GEMM micro-opt closed per pre-commit.
// ---------------------------------------------------------------------------
#define APAD 72

__global__ __launch_bounds__(256) void gemm_bf16_v2(
    const short* __restrict__ A,   // [M][K] bf16
    const short* __restrict__ Bt,  // [N][K] bf16 (transposed weights)
    short* __restrict__ Cbf,       // [M][N] bf16
    int M, int N, int K, int GX, int swz) {
  __shared__ short As[128][APAD];
  int bx, by;
  if (swz) {
    const int id = blockIdx.x;
    const int r = id & 7, u = id >> 3;
    by = u & 3;
    bx = ((u >> 2) << 3) | r;
    if (bx >= GX) return;          // uniform per block; before any barrier
  } else {
    bx = blockIdx.x; by = blockIdx.y;
  }
  const int tid  = threadIdx.x;
  const int wave = tid >> 6;
  const int lane = tid & 63;
  const int quad = lane >> 4;
  const int l16  = lane & 15;
  const int wr   = wave >> 1;
  const int wc   = wave & 1;
  const int bm = bx * 128;
  const int bn = by * 128;

  const int srow = tid >> 3;
  const int skc  = (tid & 7) * 8;

  const short* Bw = Bt + (size_t)(bn + wc * 64 + l16) * K + quad * 8;

  f32x4 acc[4][4];
  #pragma unroll
  for (int i = 0; i < 4; i++)
    #pragma unroll
    for (int jj = 0; jj < 4; jj++) acc[i][jj] = (f32x4){0, 0, 0, 0};

  // prologue: issue A-tile loads for k0=0
  int4 av[4];
  #pragma unroll
  for (int i = 0; i < 4; i++) {
    int gm = bm + srow + i * 32;
    av[i] = (int4){0, 0, 0, 0};
    if (gm < M) av[i] = *(const int4*)(A + (size_t)gm * K + skc);
  }

  for (int k0 = 0; k0 < K; k0 += 64) {
    #pragma unroll
    for (int i = 0; i < 4; i++)
      *(int4*)(&As[srow + i * 32][skc]) = av[i];
    __syncthreads();

    if (k0 + 64 < K) {
      #pragma unroll
      for (int i = 0; i < 4; i++) {
        int gm = bm + srow + i * 32;
        av[i] = (int4){0, 0, 0, 0};
        if (gm < M) av[i] = *(const int4*)(A + (size_t)gm * K + k0 + 64 + skc);
      }
    }

    bf16x8 bfr[2][4];
    #pragma unroll
    for (int kq = 0; kq < 2; kq++)
      #pragma unroll
      for (int ni = 0; ni < 4; ni++)
        bfr[kq][ni] = *(const bf16x8*)(Bw + (size_t)(ni * 16) * K + k0 + kq * 32);

    #pragma unroll
    for (int kq = 0; kq < 2; kq++) {
      bf16x8 af[4];
      #pragma unroll
      for (int mi = 0; mi < 4; mi++)
        af[mi] = *(const bf16x8*)(&As[wr * 64 + mi * 16 + l16][kq * 32 + quad * 8]);
      #pragma unroll
      for (int mi = 0; mi < 4; mi++)
        #pragma unroll
        for (int ni = 0; ni < 4; ni++)
          acc[mi][ni] = __builtin_amdgcn_mfma_f32_16x16x32_bf16(af[mi], bfr[kq][ni], acc[mi][ni], 0, 0, 0);
    }
    __syncthreads();
  }

  #pragma unroll
  for (int mi = 0; mi < 4; mi++) {
    #pragma unroll
    for (int r = 0; r < 4; r++) {
      int gm = bm + wr * 64 + mi * 16 + quad * 4 + r;
      if (gm < M) {
        #pragma unroll
        for (int ni = 0; ni < 4; ni++)
          Cbf[(size_t)gm * N + bn + wc * 64 + ni * 16 + l16] = f2bf(acc[mi][ni][r]);
      }
    }
  }
}

// ---------------------------------------------------------------------------
// Fused GATv2 edge phase, v6 body @ 64-thread blocks (R13: −25us/dispatch
// from unpacked wave scheduling). WAVE = NODE, stride-1, depth-2 EPack
// shift-register pipeline, no barriers. DO NOT deepen (v7 99.4us) and DO
// NOT slot-split (R6-era 123-127us) and DO NOT repack into 256-thread
// blocks (R12-era 89.7us).
// Over-read <= pairs[end+1] < end+16 zero pad; pad soff=0 -> valid memory.
// ---------------------------------------------------------------------------
template <int CHS, int SOFF_SHR>
__global__ __launch_bounds__(64) void gat_fused_v6(
    const short* __restrict__ xs, const short* __restrict__ xd,
    const EPack* __restrict__ pairs, const float* __restrict__ w_edge,
    const float* __restrict__ att, const float* __restrict__ bias,
    const int* __restrict__ offs, short* __restrict__ out_bf) {
  const int lane = threadIdx.x & 63;
  const int ch   = lane * 4;      // [0,256): head = lane>>4

  const f32x4 attf = *(const f32x4*)(att + ch);
  f32x4 wef[6];
  #pragma unroll
  for (int k = 0; k < 6; k++) wef[k] = *(const f32x4*)(w_edge + k * 256 + ch);
  const f32x4 b4 = *(const f32x4*)(bias + ch);

  const char* xs_b = (const char*)xs + ch * 2;   // lane's 8B within the row

  const int n = blockIdx.x;                      // 1 wave = 1 node

  uint2 xdr = *(const uint2*)(xd + (size_t)n * CHS + ch);
  f32x2 xd01, xd23; bf4_unpack(xdr, xd01, xd23);

  const int beg = offs[n], end = offs[n + 1];
  float l = 0.f;
  f32x2 acc01 = {0, 0}, acc23 = {0, 0};

  int idx = beg;
  if (idx < end) {
    // prologue: EPacks for edges 0 and 1; gather for edge 0
    const int4* pp = (const int4*)(pairs + idx);
    int4 a0 = pp[0], b0 = pp[1];
    const int4* pq = (const int4*)(pairs + idx + 1);
    int4 a1 = pq[0], b1 = pq[1];
    uint2 g0 = *(const uint2*)(xs_b + ((unsigned)a0.x >> SOFF_SHR));
    while (idx < end) {
      idx += 1;
      // gather for edge n+1 (a1 arrived a full iteration ago: no addr stall)
      uint2 g1 = *(const uint2*)(xs_b + ((unsigned)a1.x >> SOFF_SHR));
      // EPack for edge n+2 (sequential address, no load dependency)
      const int4* pn = (const int4*)(pairs + idx + 1);   // <= end+1: in pad
      int4 a2 = pn[0], b2 = pn[1];

      f32x2 x01, x23; bf4_unpack(g0, x01, x23);
      f32x2 e01 = {__int_as_float(a0.z), __int_as_float(a0.w)};
      f32x2 e23 = {__int_as_float(b0.x), __int_as_float(b0.y)};
      f32x2 e45 = {__int_as_float(b0.z), __int_as_float(b0.w)};
      f32x2 z01 = x01 + xd01, z23 = x23 + xd23;
      z01 = __builtin_elementwise_fma((f32x2)(e01.x), wef[0].xy, z01);
      z23 = __builtin_elementwise_fma((f32x2)(e01.x), wef[0].zw, z23);
      z01 = __builtin_elementwise_fma((f32x2)(e01.y), wef[1].xy, z01);
      z23 = __builtin_elementwise_fma((f32x2)(e01.y), wef[1].zw, z23);
      z01 = __builtin_elementwise_fma((f32x2)(e23.x), wef[2].xy, z01);
      z23 = __builtin_elementwise_fma((f32x2)(e23.x), wef[2].zw, z23);
      z01 = __builtin_elementwise_fma((f32x2)(e23.y), wef[3].xy, z01);
      z23 = __builtin_elementwise_fma((f32x2)(e23.y), wef[3].zw, z23);
      z01 = __builtin_elementwise_fma((f32x2)(e45.x), wef[4].xy, z01);
      z23 = __builtin_elementwise_fma((f32x2)(e45.x), wef[4].zw, z23);
      z01 = __builtin_elementwise_fma((f32x2)(e45.y), wef[5].xy, z01);
      z23 = __builtin_elementwise_fma((f32x2)(e45.y), wef[5].zw, z23);
      z01 = __builtin_elementwise_max(z01, z01 * 0.2f);
      z23 = __builtin_elementwise_max(z23, z23 * 0.2f);
      f32x2 d = z01 * attf.xy;
      d = __builtin_elementwise_fma(z23, attf.zw, d);
      float p = d.x + d.y;
      #pragma unroll
      for (int off = 1; off < 16; off <<= 1) p += __shfl_xor(p, off, 64);

      float wgt = __expf(p);          // every iteration valid: no mask
      l += wgt;
      acc01 = __builtin_elementwise_fma((f32x2)wgt, x01, acc01);
      acc23 = __builtin_elementwise_fma((f32x2)wgt, x23, acc23);

      // shift pipeline registers
      a0 = a1; b0 = b1; a1 = a2; b1 = b2; g0 = g1;
    }
  }

  // finalize: this wave owns the whole node — no merge, no barrier
  float inv = 1.f / (l + 1e-16f);
  float v0 = acc01.x * inv + b4.x;
  float v1 = acc01.y * inv + b4.y;
  float v2 = acc23.x * inv + b4.z;
  float v3 = acc23.y * inv + b4.w;
  v0 = v0 > 0.f ? v0 : (__expf(v0) - 1.f);
  v1 = v1 > 0.f ? v1 : (__expf(v1) - 1.f);
  v2 = v2 > 0.f ? v2 : (__expf(v2) - 1.f);
  v3 = v3 > 0.f ? v3 : (__expf(v3) - 1.f);
  short4 o;
  o.x = f2bf(v0); o.y = f2bf(v1); o.z = f2bf(v2); o.w = f2bf(v3);
  *(short4*)(out_bf + (size_t)n * 256 + ch) = o;   // 512B contiguous per wave
}

// ---------------------------------------------------------------------------
// Layer-3 + pool, R14: ONE NODE PER WAVE (grid = NN, block = 64). The R13
// top-5 shows pool at 70us / VALUBusy 24.8% / Occ 44.6% — latency-starved
// with 4 nodes chained sequentially per wave. Removing the nn loop keeps
// the slot structure, masking, and shfl merge IDENTICAL (bit-identical
// output) but quadruples independent waves: the exact R13 lever applied to
// the now-dominant kernel. (NOT R8's failed group-per-node rewrite.)
// H=1, CHS=128, soff>>2. global_add_pool fused via fp32 atomics.
// ---------------------------------------------------------------------------
__global__ __launch_bounds__(64) void gat_fused_pool4(
    const short* __restrict__ xs, const short* __restrict__ xd,
    const EPack* __restrict__ pairs, const float* __restrict__ w_edge,
    const float* __restrict__ att, const float* __restrict__ bias,
    const int* __restrict__ offs, const int* __restrict__ batch,
    float* __restrict__ gp) {
  constexpr int CHS = 128;
  const int lane = threadIdx.x & 63;
  const int slot = lane >> 4;
  const int pos  = lane & 15;
  const int ch   = pos * 4;
  const int n    = blockIdx.x;                   // 1 wave = 1 node

  const f32x4 attf = *(const f32x4*)(att + ch);
  f32x4 wef[6];
  #pragma unroll
  for (int k = 0; k < 6; k++) wef[k] = *(const f32x4*)(w_edge + k * 64 + ch);
  const f32x4 b4 = *(const f32x4*)(bias + ch);

  const char* xs_b = (const char*)xs + ch * 2;

  uint2 xdr = *(const uint2*)(xd + (size_t)n * CHS + ch);
  f32x2 xd01, xd23; bf4_unpack(xdr, xd01, xd23);

  const int beg = offs[n], end = offs[n + 1];
  float l = 0.f;
  f32x2 acc01 = {0, 0}, acc23 = {0, 0};

  if (beg < end) {
    const int niter = (end - beg + 3) >> 2;
    int idx = beg + slot;
    bool v = idx < end;
    const int4* pp = (const int4*)(pairs + idx);
    int4 a = pp[0], b = pp[1];
    uint2 xr = *(const uint2*)(xs_b + ((unsigned)a.x >> 2));

    for (int it = 0; it < niter; it++) {
      int4 ac = a, bc = b;
      uint2 xrc = xr;
      bool vc = v;
      idx += 4;
      v = idx < end;
      pp = (const int4*)(pairs + idx);
      a = pp[0]; b = pp[1];
      xr = *(const uint2*)(xs_b + ((unsigned)a.x >> 2));

      f32x2 x01, x23; bf4_unpack(xrc, x01, x23);
      f32x2 e01 = {__int_as_float(ac.z), __int_as_float(ac.w)};
      f32x2 e23 = {__int_as_float(bc.x), __int_as_float(bc.y)};
      f32x2 e45 = {__int_as_float(bc.z), __int_as_float(bc.w)};
      f32x2 z01 = x01 + xd01, z23 = x23 + xd23;
      z01 = __builtin_elementwise_fma((f32x2)(e01.x), wef[0].xy, z01);
      z23 = __builtin_elementwise_fma((f32x2)(e01.x), wef[0].zw, z23);
      z01 = __builtin_elementwise_fma((f32x2)(e01.y), wef[1].xy, z01);
      z23 = __builtin_elementwise_fma((f32x2)(e01.y), wef[1].zw, z23);
      z01 = __builtin_elementwise_fma((f32x2)(e23.x), wef[2].xy, z01);
      z23 = __builtin_elementwise_fma((f32x2)(e23.x), wef[2].zw, z23);
      z01 = __builtin_elementwise_fma((f32x2)(e23.y), wef[3].xy, z01);
      z23 = __builtin_elementwise_fma((f32x2)(e23.y), wef[3].zw, z23);
      z01 = __builtin_elementwise_fma((f32x2)(e45.x), wef[4].xy, z01);
      z23 = __builtin_elementwise_fma((f32x2)(e45.x), wef[4].zw, z23);
      z01 = __builtin_elementwise_fma((f32x2)(e45.y), wef[5].xy, z01);
      z23 = __builtin_elementwise_fma((f32x2)(e45.y), wef[5].zw, z23);
      z01 = __builtin_elementwise_max(z01, z01 * 0.2f);
      z23 = __builtin_elementwise_max(z23, z23 * 0.2f);
      f32x2 d = z01 * attf.xy;
      d = __builtin_elementwise_fma(z23, attf.zw, d);
      float p = d.x + d.y;
      #pragma unroll
      for (int off = 1; off < 16; off <<= 1) p += __shfl_xor(p, off, 64);

      float w = vc ? __expf(p) : 0.f;
      l += w;
      acc01 = __builtin_elementwise_fma((f32x2)w, x01, acc01);
      acc23 = __builtin_elementwise_fma((f32x2)w, x23, acc23);
    }
  }

  #pragma unroll
  for (int d = 16; d <= 32; d <<= 1) {
    l       += __shfl_xor(l, d, 64);
    acc01.x += __shfl_xor(acc01.x, d, 64);
    acc01.y += __shfl_xor(acc01.y, d, 64);
    acc23.x += __shfl_xor(acc23.x, d, 64);
    acc23.y += __shfl_xor(acc23.y, d, 64);
  }

  if (slot == 0) {
    float inv = 1.f / (l + 1e-16f);
    float v0 = acc01.x * inv + b4.x;
    float v1 = acc01.y * inv + b4.y;
    float v2 = acc23.x * inv + b4.z;
    float v3 = acc23.y * inv + b4.w;
    v0 = v0 > 0.f ? v0 : (__expf(v0) - 1.f);
    v1 = v1 > 0.f ? v1 : (__expf(v1) - 1.f);
    v2 = v2 > 0.f ? v2 : (__expf(v2) - 1.f);
    v3 = v3 > 0.f ? v3 : (__expf(v3) - 1.f);
    float* g = gp + (size_t)batch[n] * 64 + ch;
    atomicAdd(g + 0, v0);
    atomicAdd(g + 1, v1);
    atomicAdd(g + 2, v2);
    atomicAdd(g + 3, v3);
  }
}

// ---------------------------------------------------------------------------
// MLP head: out[g] = elu(g_row @ fc1 + b) @ out_w + out_b. One wave per graph.
// ---------------------------------------------------------------------------
__global__ __launch_bounds__(64) void head_mlp(const float* __restrict__ gpool,
                                               const float* __restrict__ fc1_w,
                                               const float* __restrict__ fc1_b,
                                               const float* __restrict__ out_w,
                                               const float* __restrict__ out_b,
                                               float* __restrict__ out) {
  int gr = blockIdx.x;
  int c = threadIdx.x;
  float acc = fc1_b[c];
  #pragma unroll 8
  for (int k = 0; k < HIDC; k++)
    acc += gpool[gr * HIDC + k] * fc1_w[k * HIDC + c];
  acc = acc > 0.f ? acc : (__expf(acc) - 1.f);
  float v = acc * out_w[c];
  #pragma unroll
  for (int off = 32; off > 0; off >>= 1) v += __shfl_xor(v, off, 64);
  if (c == 0) out[gr] = v + out_b[0];
}

// ---------------------------------------------------------------------------
// Host launch
// ---------------------------------------------------------------------------
extern "C" void kernel_launch(void* const* d_in, const int* in_sizes, int n_in,
                              void* d_out, int out_size, void* d_ws, size_t ws_size,
                              hipStream_t stream) {
  const float* x      = (const float*)d_in[0];
  const int*   ei     = (const int*)d_in[1];
  const float* eattr  = (const float*)d_in[2];
  const int*   batch  = (const int*)d_in[3];
  const float* w_src1 = (const float*)d_in[4];
  const float* w_dst1 = (const float*)d_in[5];
  const float* w_edge1= (const float*)d_in[6];
  const float* att1   = (const float*)d_in[7];
  const float* b1     = (const float*)d_in[8];
  const float* w_src2 = (const float*)d_in[9];
  const float* w_dst2 = (const float*)d_in[10];
  const float* w_edge2= (const float*)d_in[11];
  const float* att2   = (const float*)d_in[12];
  const float* b2     = (const float*)d_in[13];
  const float* w_src3 = (const float*)d_in[14];
  const float* w_dst3 = (const float*)d_in[15];
  const float* w_edge3= (const float*)d_in[16];
  const float* att3   = (const float*)d_in[17];
  const float* b3     = (const float*)d_in[18];
  const float* fc1_w  = (const float*)d_in[19];
  const float* fc1_b  = (const float*)d_in[20];
  const float* out_w  = (const float*)d_in[21];
  const float* out_b  = (const float*)d_in[22];

  const int* src = ei;
  const int* dst = ei + EE;

  char* p = (char*)d_ws;
  auto carve = [&](size_t bytes) -> void* {
    void* r = (void*)p;
    p += (bytes + 255) & ~(size_t)255;
    return r;
  };
  short* xsd_bf = (short*)carve((size_t)NN * 512 * sizeof(short));  // 51.2 MB bf16 [xs|xd]
  short* xbf1   = (short*)carve((size_t)NN * FF * sizeof(short));   // 12.8 MB
  short* hbf    = (short*)carve((size_t)NN * HC * sizeof(short));   // 25.6 MB
  short* wtcat1 = (short*)carve((size_t)512 * FF * sizeof(short));
  short* wtcat2 = (short*)carve((size_t)512 * HC * sizeof(short));
  short* wtcat3 = (short*)carve((size_t)128 * HC * sizeof(short));
  float* gp     = (float*)carve((size_t)GG * HIDC * sizeof(float));
  int* deg      = (int*)carve((size_t)NN * sizeof(int));
  int* offs     = (int*)carve((size_t)(NN + 1) * sizeof(int));
  int* cur      = (int*)carve((size_t)NN * sizeof(int));
  int* bsum     = (int*)carve((size_t)SCAN_B * sizeof(int));
  EPack* pairs  = (EPack*)carve((size_t)(EE + 16) * sizeof(EPack)); // 16 MB
  (void)ws_size; (void)n_in; (void)in_sizes; (void)out_size;

  const int GM128 = (NN + 127) / 128;  // 391
  const int GSWZ  = 8 * 4 * ((GM128 + 7) / 8);  // 1568: swizzled 1D grid (4 idle)

  // --- zero deg + gp (graph-capture-legal async memsets) ---
  hipMemsetAsync(deg, 0, (size_t)NN * sizeof(int), stream);
  hipMemsetAsync(gp, 0, (size_t)GG * HIDC * sizeof(float), stream);

  // --- Prep: cvt x, cvt weights, zero pairs-tail, count deg (ONE dispatch) ---
  WtJobs j;
  j.w[0] = w_src1; j.o[0] = wtcat1;                       j.K[0] = FF; j.N[0] = HC;
  j.w[1] = w_dst1; j.o[1] = wtcat1 + (size_t)HC * FF;     j.K[1] = FF; j.N[1] = HC;
  j.w[2] = w_src2; j.o[2] = wtcat2;                       j.K[2] = HC; j.N[2] = HC;
  j.w[3] = w_dst2; j.o[3] = wtcat2 + (size_t)HC * HC;     j.K[3] = HC; j.N[3] = HC;
  j.w[4] = w_src3; j.o[4] = wtcat3;                       j.K[4] = HC; j.N[4] = HIDC;
  j.w[5] = w_dst3; j.o[5] = wtcat3 + (size_t)HIDC * HC;   j.K[5] = HC; j.N[5] = HIDC;
  j.cum[0] = 0;
  for (int s = 0; s < 6; s++) j.cum[s + 1] = j.cum[s] + j.K[s] * j.N[s];
  prep_all<<<(NN * FF + 255) / 256, 256, 0, stream>>>(x, xbf1, dst, deg,
                                                      (int*)(pairs + EE), j);

  // --- CSR build (shared by all layers); parallel 3-stage scan ---
  scan_stage1<<<SCAN_B, SCAN_T, 0, stream>>>(deg, bsum);
  scan_stage2<<<1, 64, 0, stream>>>(bsum);
  scan_stage3<<<SCAN_B, SCAN_T, 0, stream>>>(deg, bsum, offs, cur);
  fill_edges<<<(EE + 255) / 256, 256, 0, stream>>>(src, dst, eattr, cur, pairs);

  // --- Layer 1: one GEMM for [xs|xd] (N=512, K=128), XCD-swizzled grid ---
  gemm_bf16_v2<<<dim3(GSWZ), 256, 0, stream>>>(xbf1, wtcat1, xsd_bf, NN, 512, FF,
                                               GM128, 1);
  gat_fused_v6<512, 0><<<NN, 64, 0, stream>>>(xsd_bf, xsd_bf + HC, pairs,
                                              w_edge1, att1, b1, offs, hbf);

  // --- Layer 2: N=512, K=256, XCD-swizzled grid ---
  gemm_bf16_v2<<<dim3(GSWZ), 256, 0, stream>>>(hbf, wtcat2, xsd_bf, NN, 512, HC,
                                               GM128, 1);
  gat_fused_v6<512, 0><<<NN, 64, 0, stream>>>(xsd_bf, xsd_bf + HC, pairs,
                                              w_edge2, att2, b2, offs, hbf);

  // --- Layer 3: N=128, K=256 (single bn-block: no A re-read, no swizzle) ---
  gemm_bf16_v2<<<dim3(GM128, 1), 256, 0, stream>>>(hbf, wtcat3, xsd_bf, NN, 128, HC,
                                                   GM128, 0);
  gat_fused_pool4<<<NN, 64, 0, stream>>>(xsd_bf, xsd_bf + HIDC, pairs,
                                         w_edge3, att3, b3, offs, batch, gp);

  // --- MLP head ---
  head_mlp<<<GG, 64, 0, stream>>>(gp, fc1_w, fc1_b, out_w, out_b, (float*)d_out);
}

// Round 15
// 421.136 us; speedup vs baseline: 1.1368x; 1.1368x over previous
//
#include <hip/hip_runtime.h>
#include <hip/hip_bf16.h>
#include <cstddef>
#include <cstdint>

// Problem constants (match reference setup_inputs)
constexpr int NN    = 50000;   // nodes
constexpr int EE    = 500000;  // edges
constexpr int FF    = 128;     // input feature dim
constexpr int HIDC  = 64;      // hidden per head
constexpr int NHEAD = 4;
constexpr int HC    = 256;     // NHEAD * HIDC
constexpr int GG    = 256;     // graphs

typedef __attribute__((ext_vector_type(2))) float f32x2;
typedef __attribute__((ext_vector_type(4))) float f32x4;
typedef __attribute__((ext_vector_type(8))) short bf16x8;

// CSR edge record: src byte-offset (src*1024) + the 6 edge features. 32 B.
struct __align__(16) EPack { int soff; int pad; float e0, e1, e2, e3, e4, e5; };

// round-to-nearest-even fp32 -> bf16 (as short)
__device__ inline short f2bf(float f) {
  union { float f; unsigned u; } v; v.f = f;
  unsigned r = v.u + 0x7fffu + ((v.u >> 16) & 1u);
  return (short)(r >> 16);
}

// unpack 4 bf16 (as uint2) -> two f32x2
__device__ inline void bf4_unpack(uint2 v, f32x2& a, f32x2& b) {
  union { unsigned u; float f; } t;
  t.u = v.x << 16;          a.x = t.f;
  t.u = v.x & 0xffff0000u;  a.y = t.f;
  t.u = v.y << 16;          b.x = t.f;
  t.u = v.y & 0xffff0000u;  b.y = t.f;
}

// ---------------------------------------------------------------------------
// Weight-conversion job table (all 6 matrices)
// ---------------------------------------------------------------------------
struct WtJobs {
  const float* w[6];
  short* o[6];
  int K[6], N[6];
  int cum[7];
};

// ---------------------------------------------------------------------------
// Prep kernel: convert x -> bf16, convert all weights (transpose+bf16),
// zero pairs tail, AND count degrees (deg/gp zeroed by hipMemsetAsync).
// ---------------------------------------------------------------------------
__global__ void prep_all(const float* __restrict__ x, short* __restrict__ xbf,
                         const int* __restrict__ dst, int* __restrict__ deg,
                         int* __restrict__ pairs_tail, WtJobs j) {
  int i = blockIdx.x * blockDim.x + threadIdx.x;
  if (i < NN * FF) xbf[i] = f2bf(x[i]);
  if (i < EE) atomicAdd(&deg[dst[i]], 1);      // folded count_deg
  if (i < 16 * 8) pairs_tail[i] = 0;           // 16 EPack tail entries
  if (i < j.cum[6]) {
    int s = 0;
    while (i >= j.cum[s + 1]) s++;
    int li = i - j.cum[s];
    int K = j.K[s], N = j.N[s];
    int n = li / K, k = li - n * K;
    j.o[s][li] = f2bf(j.w[s][k * N + n]);
  }
}

constexpr int SCAN_T = 256;   // threads per scan block
constexpr int SCAN_B = 64;    // scan blocks
constexpr int SCHUNK = 4;     // elems per thread (64*256*4 = 65536 >= NN)

// Stage 1: per-block sums of deg
__global__ __launch_bounds__(SCAN_T) void scan_stage1(const int* __restrict__ deg,
                                                      int* __restrict__ bsum) {
  __shared__ int red[SCAN_T];
  const int t = threadIdx.x, b = blockIdx.x;
  int base = (b * SCAN_T + t) * SCHUNK;
  int s = 0;
  #pragma unroll
  for (int i = 0; i < SCHUNK; i++) {
    int idx = base + i;
    if (idx < NN) s += deg[idx];
  }
  red[t] = s;
  __syncthreads();
  for (int off = SCAN_T / 2; off > 0; off >>= 1) {
    if (t < off) red[t] += red[t + off];
    __syncthreads();
  }
  if (t == 0) bsum[b] = red[0];
}

// Stage 2: inclusive scan of the 64 block sums (one wave)
__global__ __launch_bounds__(64) void scan_stage2(int* __restrict__ bsum) {
  int t = threadIdx.x;
  int v = bsum[t];
  #pragma unroll
  for (int off = 1; off < 64; off <<= 1) {
    int o = __shfl_up(v, off, 64);
    if (t >= off) v += o;
  }
  bsum[t] = v;   // inclusive
}

// Stage 3: full exclusive prefix -> offs/cur (+ offs[NN] = total)
__global__ __launch_bounds__(SCAN_T) void scan_stage3(const int* __restrict__ deg,
                                                      const int* __restrict__ bsum,
                                                      int* __restrict__ offs,
                                                      int* __restrict__ cur) {
  __shared__ int red[SCAN_T];
  const int t = threadIdx.x, b = blockIdx.x;
  const int base = (b * SCAN_T + t) * SCHUNK;
  int local[SCHUNK];
  int s = 0;
  #pragma unroll
  for (int i = 0; i < SCHUNK; i++) {
    int idx = base + i;
    local[i] = (idx < NN) ? deg[idx] : 0;
    s += local[i];
  }
  red[t] = s;
  __syncthreads();
  for (int off = 1; off < SCAN_T; off <<= 1) {   // Hillis-Steele inclusive
    int v = (t >= off) ? red[t - off] : 0;
    __syncthreads();
    red[t] += v;
    __syncthreads();
  }
  const int blockBase = (b == 0) ? 0 : bsum[b - 1];
  int run = blockBase + red[t] - s;              // exclusive prefix for this thread
  #pragma unroll
  for (int i = 0; i < SCHUNK; i++) {
    int idx = base + i;
    if (idx < NN) {
      offs[idx] = run; cur[idx] = run; run += local[i];
    }
  }
  if (b == SCAN_B - 1 && t == SCAN_T - 1) offs[NN] = run;  // == EE
}

__global__ void fill_edges(const int* __restrict__ src, const int* __restrict__ dst,
                           const float* __restrict__ eattr,
                           int* __restrict__ cur, EPack* __restrict__ pairs) {
  int i = blockIdx.x * blockDim.x + threadIdx.x;
  if (i < EE) {
    int pos = atomicAdd(&cur[dst[i]], 1);
    const float* ea = eattr + i * 6;
    int4* q = (int4*)(pairs + pos);
    int4 w0, w1;
    w0.x = src[i] * 1024; w0.y = 0;
    w0.z = __float_as_int(ea[0]); w0.w = __float_as_int(ea[1]);
    w1.x = __float_as_int(ea[2]); w1.y = __float_as_int(ea[3]);
    w1.z = __float_as_int(ea[4]); w1.w = __float_as_int(ea[5]);
    q[0] = w0; q[1] = w1;
  }
}

// ---------------------------------------------------------------------------
// bf16 MFMA GEMM, 128x128 tile, BK=64, 256 threads (2x2 waves of 64x64).
// B fragments direct from global (L2-resident weights); LDS only for A.
// R5: XCD-co-location swizzle. R11: A-tile issue-early/write-late (−9us).
// R12: all-B hoist (neutral, kept). GEMM micro-opt closed per pre-commit.
// ---------------------------------------------------------------------------
#define APAD 72

__global__ __launch_bounds__(256) void gemm_bf16_v2(
    const short* __restrict__ A,   // [M][K] bf16
    const short* __restrict__ Bt,  // [N][K] bf16 (transposed weights)
    short* __restrict__ Cbf,       // [M][N] bf16
    int M, int N, int K, int GX, int swz) {
  __shared__ short As[128][APAD];
  int bx, by;
  if (swz) {
    const int id = blockIdx.x;
    const int r = id & 7, u = id >> 3;
    by = u & 3;
    bx = ((u >> 2) << 3) | r;
    if (bx >= GX) return;          // uniform per block; before any barrier
  } else {
    bx = blockIdx.x; by = blockIdx.y;
  }
  const int tid  = threadIdx.x;
  const int wave = tid >> 6;
  const int lane = tid & 63;
  const int quad = lane >> 4;
  const int l16  = lane & 15;
  const int wr   = wave >> 1;
  const int wc   = wave & 1;
  const int bm = bx * 128;
  const int bn = by * 128;

  const int srow = tid >> 3;
  const int skc  = (tid & 7) * 8;

  const short* Bw = Bt + (size_t)(bn + wc * 64 + l16) * K + quad * 8;

  f32x4 acc[4][4];
  #pragma unroll
  for (int i = 0; i < 4; i++)
    #pragma unroll
    for (int jj = 0; jj < 4; jj++) acc[i][jj] = (f32x4){0, 0, 0, 0};

  // prologue: issue A-tile loads for k0=0
  int4 av[4];
  #pragma unroll
  for (int i = 0; i < 4; i++) {
    int gm = bm + srow + i * 32;
    av[i] = (int4){0, 0, 0, 0};
    if (gm < M) av[i] = *(const int4*)(A + (size_t)gm * K + skc);
  }

  for (int k0 = 0; k0 < K; k0 += 64) {
    #pragma unroll
    for (int i = 0; i < 4; i++)
      *(int4*)(&As[srow + i * 32][skc]) = av[i];
    __syncthreads();

    if (k0 + 64 < K) {
      #pragma unroll
      for (int i = 0; i < 4; i++) {
        int gm = bm + srow + i * 32;
        av[i] = (int4){0, 0, 0, 0};
        if (gm < M) av[i] = *(const int4*)(A + (size_t)gm * K + k0 + 64 + skc);
      }
    }

    bf16x8 bfr[2][4];
    #pragma unroll
    for (int kq = 0; kq < 2; kq++)
      #pragma unroll
      for (int ni = 0; ni < 4; ni++)
        bfr[kq][ni] = *(const bf16x8*)(Bw + (size_t)(ni * 16) * K + k0 + kq * 32);

    #pragma unroll
    for (int kq = 0; kq < 2; kq++) {
      bf16x8 af[4];
      #pragma unroll
      for (int mi = 0; mi < 4; mi++)
        af[mi] = *(const bf16x8*)(&As[wr * 64 + mi * 16 + l16][kq * 32 + quad * 8]);
      #pragma unroll
      for (int mi = 0; mi < 4; mi++)
        #pragma unroll
        for (int ni = 0; ni < 4; ni++)
          acc[mi][ni] = __builtin_amdgcn_mfma_f32_16x16x32_bf16(af[mi], bfr[kq][ni], acc[mi][ni], 0, 0, 0);
    }
    __syncthreads();
  }

  #pragma unroll
  for (int mi = 0; mi < 4; mi++) {
    #pragma unroll
    for (int r = 0; r < 4; r++) {
      int gm = bm + wr * 64 + mi * 16 + quad * 4 + r;
      if (gm < M) {
        #pragma unroll
        for (int ni = 0; ni < 4; ni++)
          Cbf[(size_t)gm * N + bn + wc * 64 + ni * 16 + l16] = f2bf(acc[mi][ni][r]);
      }
    }
  }
}

// ---------------------------------------------------------------------------
// Fused GATv2 edge phase, v6 body @ 64-thread blocks (R13: −25us/dispatch
// from unpacked wave scheduling). WAVE = NODE, stride-1, depth-2 EPack
// shift-register pipeline, no barriers. DO NOT deepen (v7 99.4us), DO NOT
// slot-split (R6-era 123-127us), DO NOT repack into 256-thread blocks
// (R12-era 89.7us).
// Over-read <= pairs[end+1] < end+16 zero pad; pad soff=0 -> valid memory.
// ---------------------------------------------------------------------------
template <int CHS, int SOFF_SHR>
__global__ __launch_bounds__(64) void gat_fused_v6(
    const short* __restrict__ xs, const short* __restrict__ xd,
    const EPack* __restrict__ pairs, const float* __restrict__ w_edge,
    const float* __restrict__ att, const float* __restrict__ bias,
    const int* __restrict__ offs, short* __restrict__ out_bf) {
  const int lane = threadIdx.x & 63;
  const int ch   = lane * 4;      // [0,256): head = lane>>4

  const f32x4 attf = *(const f32x4*)(att + ch);
  f32x4 wef[6];
  #pragma unroll
  for (int k = 0; k < 6; k++) wef[k] = *(const f32x4*)(w_edge + k * 256 + ch);
  const f32x4 b4 = *(const f32x4*)(bias + ch);

  const char* xs_b = (const char*)xs + ch * 2;   // lane's 8B within the row

  const int n = blockIdx.x;                      // 1 wave = 1 node

  uint2 xdr = *(const uint2*)(xd + (size_t)n * CHS + ch);
  f32x2 xd01, xd23; bf4_unpack(xdr, xd01, xd23);

  const int beg = offs[n], end = offs[n + 1];
  float l = 0.f;
  f32x2 acc01 = {0, 0}, acc23 = {0, 0};

  int idx = beg;
  if (idx < end) {
    // prologue: EPacks for edges 0 and 1; gather for edge 0
    const int4* pp = (const int4*)(pairs + idx);
    int4 a0 = pp[0], b0 = pp[1];
    const int4* pq = (const int4*)(pairs + idx + 1);
    int4 a1 = pq[0], b1 = pq[1];
    uint2 g0 = *(const uint2*)(xs_b + ((unsigned)a0.x >> SOFF_SHR));
    while (idx < end) {
      idx += 1;
      // gather for edge n+1 (a1 arrived a full iteration ago: no addr stall)
      uint2 g1 = *(const uint2*)(xs_b + ((unsigned)a1.x >> SOFF_SHR));
      // EPack for edge n+2 (sequential address, no load dependency)
      const int4* pn = (const int4*)(pairs + idx + 1);   // <= end+1: in pad
      int4 a2 = pn[0], b2 = pn[1];

      f32x2 x01, x23; bf4_unpack(g0, x01, x23);
      f32x2 e01 = {__int_as_float(a0.z), __int_as_float(a0.w)};
      f32x2 e23 = {__int_as_float(b0.x), __int_as_float(b0.y)};
      f32x2 e45 = {__int_as_float(b0.z), __int_as_float(b0.w)};
      f32x2 z01 = x01 + xd01, z23 = x23 + xd23;
      z01 = __builtin_elementwise_fma((f32x2)(e01.x), wef[0].xy, z01);
      z23 = __builtin_elementwise_fma((f32x2)(e01.x), wef[0].zw, z23);
      z01 = __builtin_elementwise_fma((f32x2)(e01.y), wef[1].xy, z01);
      z23 = __builtin_elementwise_fma((f32x2)(e01.y), wef[1].zw, z23);
      z01 = __builtin_elementwise_fma((f32x2)(e23.x), wef[2].xy, z01);
      z23 = __builtin_elementwise_fma((f32x2)(e23.x), wef[2].zw, z23);
      z01 = __builtin_elementwise_fma((f32x2)(e23.y), wef[3].xy, z01);
      z23 = __builtin_elementwise_fma((f32x2)(e23.y), wef[3].zw, z23);
      z01 = __builtin_elementwise_fma((f32x2)(e45.x), wef[4].xy, z01);
      z23 = __builtin_elementwise_fma((f32x2)(e45.x), wef[4].zw, z23);
      z01 = __builtin_elementwise_fma((f32x2)(e45.y), wef[5].xy, z01);
      z23 = __builtin_elementwise_fma((f32x2)(e45.y), wef[5].zw, z23);
      z01 = __builtin_elementwise_max(z01, z01 * 0.2f);
      z23 = __builtin_elementwise_max(z23, z23 * 0.2f);
      f32x2 d = z01 * attf.xy;
      d = __builtin_elementwise_fma(z23, attf.zw, d);
      float p = d.x + d.y;
      #pragma unroll
      for (int off = 1; off < 16; off <<= 1) p += __shfl_xor(p, off, 64);

      float wgt = __expf(p);          // every iteration valid: no mask
      l += wgt;
      acc01 = __builtin_elementwise_fma((f32x2)wgt, x01, acc01);
      acc23 = __builtin_elementwise_fma((f32x2)wgt, x23, acc23);

      // shift pipeline registers
      a0 = a1; b0 = b1; a1 = a2; b1 = b2; g0 = g1;
    }
  }

  // finalize: this wave owns the whole node — no merge, no barrier
  float inv = 1.f / (l + 1e-16f);
  float v0 = acc01.x * inv + b4.x;
  float v1 = acc01.y * inv + b4.y;
  float v2 = acc23.x * inv + b4.z;
  float v3 = acc23.y * inv + b4.w;
  v0 = v0 > 0.f ? v0 : (__expf(v0) - 1.f);
  v1 = v1 > 0.f ? v1 : (__expf(v1) - 1.f);
  v2 = v2 > 0.f ? v2 : (__expf(v2) - 1.f);
  v3 = v3 > 0.f ? v3 : (__expf(v3) - 1.f);
  short4 o;
  o.x = f2bf(v0); o.y = f2bf(v1); o.z = f2bf(v2); o.w = f2bf(v3);
  *(short4*)(out_bf + (size_t)n * 256 + ch) = o;   // 512B contiguous per wave
}

// ---------------------------------------------------------------------------
// Layer-3 + pool, R15: REVERTED to R13 structure (4 nodes sequential per
// wave, 64-thread blocks, grid NN/4 — measured 70.1us; R14's 1-node-per-
// wave was 99.5us: pool's ~2.5-iteration chains make per-node setup+prologue
// dominate, the R6 lesson). ONE delta kept: the atomic epilogue is spread
// across ALL 64 lanes (1 atomicAdd each) instead of 4 serial atomics on the
// 16 slot-0 lanes — after the full butterfly all slots hold identical sums,
// so lane (slot,pos) writes channel pos*4+slot. Same values; atomic order
// differs (already nondeterministic fp32 atomics).
// H=1, CHS=128, soff>>2.
// ---------------------------------------------------------------------------
__global__ __launch_bounds__(64) void gat_fused_pool4(
    const short* __restrict__ xs, const short* __restrict__ xd,
    const EPack* __restrict__ pairs, const float* __restrict__ w_edge,
    const float* __restrict__ att, const float* __restrict__ bias,
    const int* __restrict__ offs, const int* __restrict__ batch,
    float* __restrict__ gp) {
  constexpr int CHS = 128;
  const int lane = threadIdx.x & 63;
  const int slot = lane >> 4;
  const int pos  = lane & 15;
  const int ch   = pos * 4;
  const int nbase = blockIdx.x * 4;              // 1 wave, 4 nodes sequential

  const f32x4 attf = *(const f32x4*)(att + ch);
  f32x4 wef[6];
  #pragma unroll
  for (int k = 0; k < 6; k++) wef[k] = *(const f32x4*)(w_edge + k * 64 + ch);
  const f32x4 b4 = *(const f32x4*)(bias + ch);

  const char* xs_b = (const char*)xs + ch * 2;

  #pragma unroll
  for (int nn = 0; nn < 4; nn++) {
    const int n = nbase + nn;
    if (n >= NN) break;

    uint2 xdr = *(const uint2*)(xd + (size_t)n * CHS + ch);
    f32x2 xd01, xd23; bf4_unpack(xdr, xd01, xd23);

    const int beg = offs[n], end = offs[n + 1];
    float l = 0.f;
    f32x2 acc01 = {0, 0}, acc23 = {0, 0};

    if (beg < end) {
      const int niter = (end - beg + 3) >> 2;
      int idx = beg + slot;
      bool v = idx < end;
      const int4* pp = (const int4*)(pairs + idx);
      int4 a = pp[0], b = pp[1];
      uint2 xr = *(const uint2*)(xs_b + ((unsigned)a.x >> 2));

      for (int it = 0; it < niter; it++) {
        int4 ac = a, bc = b;
        uint2 xrc = xr;
        bool vc = v;
        idx += 4;
        v = idx < end;
        pp = (const int4*)(pairs + idx);
        a = pp[0]; b = pp[1];
        xr = *(const uint2*)(xs_b + ((unsigned)a.x >> 2));

        f32x2 x01, x23; bf4_unpack(xrc, x01, x23);
        f32x2 e01 = {__int_as_float(ac.z), __int_as_float(ac.w)};
        f32x2 e23 = {__int_as_float(bc.x), __int_as_float(bc.y)};
        f32x2 e45 = {__int_as_float(bc.z), __int_as_float(bc.w)};
        f32x2 z01 = x01 + xd01, z23 = x23 + xd23;
        z01 = __builtin_elementwise_fma((f32x2)(e01.x), wef[0].xy, z01);
        z23 = __builtin_elementwise_fma((f32x2)(e01.x), wef[0].zw, z23);
        z01 = __builtin_elementwise_fma((f32x2)(e01.y), wef[1].xy, z01);
        z23 = __builtin_elementwise_fma((f32x2)(e01.y), wef[1].zw, z23);
        z01 = __builtin_elementwise_fma((f32x2)(e23.x), wef[2].xy, z01);
        z23 = __builtin_elementwise_fma((f32x2)(e23.x), wef[2].zw, z23);
        z01 = __builtin_elementwise_fma((f32x2)(e23.y), wef[3].xy, z01);
        z23 = __builtin_elementwise_fma((f32x2)(e23.y), wef[3].zw, z23);
        z01 = __builtin_elementwise_fma((f32x2)(e45.x), wef[4].xy, z01);
        z23 = __builtin_elementwise_fma((f32x2)(e45.x), wef[4].zw, z23);
        z01 = __builtin_elementwise_fma((f32x2)(e45.y), wef[5].xy, z01);
        z23 = __builtin_elementwise_fma((f32x2)(e45.y), wef[5].zw, z23);
        z01 = __builtin_elementwise_max(z01, z01 * 0.2f);
        z23 = __builtin_elementwise_max(z23, z23 * 0.2f);
        f32x2 d = z01 * attf.xy;
        d = __builtin_elementwise_fma(z23, attf.zw, d);
        float p = d.x + d.y;
        #pragma unroll
        for (int off = 1; off < 16; off <<= 1) p += __shfl_xor(p, off, 64);

        float w = vc ? __expf(p) : 0.f;
        l += w;
        acc01 = __builtin_elementwise_fma((f32x2)w, x01, acc01);
        acc23 = __builtin_elementwise_fma((f32x2)w, x23, acc23);
      }
    }

    #pragma unroll
    for (int d = 16; d <= 32; d <<= 1) {
      l       += __shfl_xor(l, d, 64);
      acc01.x += __shfl_xor(acc01.x, d, 64);
      acc01.y += __shfl_xor(acc01.y, d, 64);
      acc23.x += __shfl_xor(acc23.x, d, 64);
      acc23.y += __shfl_xor(acc23.y, d, 64);
    }

    // all 4 slots now hold identical merged sums: spread the 64 atomics
    // across all 64 lanes (1 each) instead of 4 serial per slot-0 lane
    {
      float inv = 1.f / (l + 1e-16f);
      float v0 = acc01.x * inv + b4.x;
      float v1 = acc01.y * inv + b4.y;
      float v2 = acc23.x * inv + b4.z;
      float v3 = acc23.y * inv + b4.w;
      v0 = v0 > 0.f ? v0 : (__expf(v0) - 1.f);
      v1 = v1 > 0.f ? v1 : (__expf(v1) - 1.f);
      v2 = v2 > 0.f ? v2 : (__expf(v2) - 1.f);
      v3 = v3 > 0.f ? v3 : (__expf(v3) - 1.f);
      float sel = (slot == 0) ? v0 : (slot == 1) ? v1 : (slot == 2) ? v2 : v3;
      atomicAdd(gp + (size_t)batch[n] * 64 + ch + slot, sel);
    }
  }
}

// ---------------------------------------------------------------------------
// MLP head: out[g] = elu(g_row @ fc1 + b) @ out_w + out_b. One wave per graph.
// ---------------------------------------------------------------------------
__global__ __launch_bounds__(64) void head_mlp(const float* __restrict__ gpool,
                                               const float* __restrict__ fc1_w,
                                               const float* __restrict__ fc1_b,
                                               const float* __restrict__ out_w,
                                               const float* __restrict__ out_b,
                                               float* __restrict__ out) {
  int gr = blockIdx.x;
  int c = threadIdx.x;
  float acc = fc1_b[c];
  #pragma unroll 8
  for (int k = 0; k < HIDC; k++)
    acc += gpool[gr * HIDC + k] * fc1_w[k * HIDC + c];
  acc = acc > 0.f ? acc : (__expf(acc) - 1.f);
  float v = acc * out_w[c];
  #pragma unroll
  for (int off = 32; off > 0; off >>= 1) v += __shfl_xor(v, off, 64);
  if (c == 0) out[gr] = v + out_b[0];
}

// ---------------------------------------------------------------------------
// Host launch
// ---------------------------------------------------------------------------
extern "C" void kernel_launch(void* const* d_in, const int* in_sizes, int n_in,
                              void* d_out, int out_size, void* d_ws, size_t ws_size,
                              hipStream_t stream) {
  const float* x      = (const float*)d_in[0];
  const int*   ei     = (const int*)d_in[1];
  const float* eattr  = (const float*)d_in[2];
  const int*   batch  = (const int*)d_in[3];
  const float* w_src1 = (const float*)d_in[4];
  const float* w_dst1 = (const float*)d_in[5];
  const float* w_edge1= (const float*)d_in[6];
  const float* att1   = (const float*)d_in[7];
  const float* b1     = (const float*)d_in[8];
  const float* w_src2 = (const float*)d_in[9];
  const float* w_dst2 = (const float*)d_in[10];
  const float* w_edge2= (const float*)d_in[11];
  const float* att2   = (const float*)d_in[12];
  const float* b2     = (const float*)d_in[13];
  const float* w_src3 = (const float*)d_in[14];
  const float* w_dst3 = (const float*)d_in[15];
  const float* w_edge3= (const float*)d_in[16];
  const float* att3   = (const float*)d_in[17];
  const float* b3     = (const float*)d_in[18];
  const float* fc1_w  = (const float*)d_in[19];
  const float* fc1_b  = (const float*)d_in[20];
  const float* out_w  = (const float*)d_in[21];
  const float* out_b  = (const float*)d_in[22];

  const int* src = ei;
  const int* dst = ei + EE;

  char* p = (char*)d_ws;
  auto carve = [&](size_t bytes) -> void* {
    void* r = (void*)p;
    p += (bytes + 255) & ~(size_t)255;
    return r;
  };
  short* xsd_bf = (short*)carve((size_t)NN * 512 * sizeof(short));  // 51.2 MB bf16 [xs|xd]
  short* xbf1   = (short*)carve((size_t)NN * FF * sizeof(short));   // 12.8 MB
  short* hbf    = (short*)carve((size_t)NN * HC * sizeof(short));   // 25.6 MB
  short* wtcat1 = (short*)carve((size_t)512 * FF * sizeof(short));
  short* wtcat2 = (short*)carve((size_t)512 * HC * sizeof(short));
  short* wtcat3 = (short*)carve((size_t)128 * HC * sizeof(short));
  float* gp     = (float*)carve((size_t)GG * HIDC * sizeof(float));
  int* deg      = (int*)carve((size_t)NN * sizeof(int));
  int* offs     = (int*)carve((size_t)(NN + 1) * sizeof(int));
  int* cur      = (int*)carve((size_t)NN * sizeof(int));
  int* bsum     = (int*)carve((size_t)SCAN_B * sizeof(int));
  EPack* pairs  = (EPack*)carve((size_t)(EE + 16) * sizeof(EPack)); // 16 MB
  (void)ws_size; (void)n_in; (void)in_sizes; (void)out_size;

  const int GM128 = (NN + 127) / 128;  // 391
  const int GSWZ  = 8 * 4 * ((GM128 + 7) / 8);  // 1568: swizzled 1D grid (4 idle)

  // --- zero deg + gp (graph-capture-legal async memsets) ---
  hipMemsetAsync(deg, 0, (size_t)NN * sizeof(int), stream);
  hipMemsetAsync(gp, 0, (size_t)GG * HIDC * sizeof(float), stream);

  // --- Prep: cvt x, cvt weights, zero pairs-tail, count deg (ONE dispatch) ---
  WtJobs j;
  j.w[0] = w_src1; j.o[0] = wtcat1;                       j.K[0] = FF; j.N[0] = HC;
  j.w[1] = w_dst1; j.o[1] = wtcat1 + (size_t)HC * FF;     j.K[1] = FF; j.N[1] = HC;
  j.w[2] = w_src2; j.o[2] = wtcat2;                       j.K[2] = HC; j.N[2] = HC;
  j.w[3] = w_dst2; j.o[3] = wtcat2 + (size_t)HC * HC;     j.K[3] = HC; j.N[3] = HC;
  j.w[4] = w_src3; j.o[4] = wtcat3;                       j.K[4] = HC; j.N[4] = HIDC;
  j.w[5] = w_dst3; j.o[5] = wtcat3 + (size_t)HIDC * HC;   j.K[5] = HC; j.N[5] = HIDC;
  j.cum[0] = 0;
  for (int s = 0; s < 6; s++) j.cum[s + 1] = j.cum[s] + j.K[s] * j.N[s];
  prep_all<<<(NN * FF + 255) / 256, 256, 0, stream>>>(x, xbf1, dst, deg,
                                                      (int*)(pairs + EE), j);

  // --- CSR build (shared by all layers); parallel 3-stage scan ---
  scan_stage1<<<SCAN_B, SCAN_T, 0, stream>>>(deg, bsum);
  scan_stage2<<<1, 64, 0, stream>>>(bsum);
  scan_stage3<<<SCAN_B, SCAN_T, 0, stream>>>(deg, bsum, offs, cur);
  fill_edges<<<(EE + 255) / 256, 256, 0, stream>>>(src, dst, eattr, cur, pairs);

  // --- Layer 1: one GEMM for [xs|xd] (N=512, K=128), XCD-swizzled grid ---
  gemm_bf16_v2<<<dim3(GSWZ), 256, 0, stream>>>(xbf1, wtcat1, xsd_bf, NN, 512, FF,
                                               GM128, 1);
  gat_fused_v6<512, 0><<<NN, 64, 0, stream>>>(xsd_bf, xsd_bf + HC, pairs,
                                              w_edge1, att1, b1, offs, hbf);

  // --- Layer 2: N=512, K=256, XCD-swizzled grid ---
  gemm_bf16_v2<<<dim3(GSWZ), 256, 0, stream>>>(hbf, wtcat2, xsd_bf, NN, 512, HC,
                                               GM128, 1);
  gat_fused_v6<512, 0><<<NN, 64, 0, stream>>>(xsd_bf, xsd_bf + HC, pairs,
                                              w_edge2, att2, b2, offs, hbf);

  // --- Layer 3: N=128, K=256 (single bn-block: no A re-read, no swizzle) ---
  gemm_bf16_v2<<<dim3(GM128, 1), 256, 0, stream>>>(hbf, wtcat3, xsd_bf, NN, 128, HC,
                                                   GM128, 0);
  gat_fused_pool4<<<(NN + 3) / 4, 64, 0, stream>>>(xsd_bf, xsd_bf + HIDC, pairs,
                                                   w_edge3, att3, b3, offs, batch, gp);

  // --- MLP head ---
  head_mlp<<<GG, 64, 0, stream>>>(gp, fc1_w, fc1_b, out_w, out_b, (float*)d_out);
}